// Round 5
// baseline (520.824 us; speedup 1.0000x reference)
//
#include <hip/hip_runtime.h>
#include <math.h>

#define LMAXP1 33
#define EDIM   256
#define CINF   10000.0f
#define FBIG   3.0e38f

// ---------------------------------------------------------------------------
// GEMM (NT, fused bias+relu): C[Mtot x 256] = relu(A @ W^T + b)
// ---------------------------------------------------------------------------
__global__ __launch_bounds__(256)
void k_embed_gemm(const float* __restrict__ S0, int n0,
                  const float* __restrict__ S1, int n1,
                  const float* __restrict__ S2,
                  const float* __restrict__ W, const float* __restrict__ bias,
                  float* __restrict__ C, int Mtot, int K) {
    __shared__ alignas(16) float As[16][68];   // transposed: As[k][row]
    __shared__ alignas(16) float Bs[16][68];
    const int tid  = threadIdx.x;
    const int tx   = tid & 15, ty = tid >> 4;
    const int m0   = blockIdx.x * 64, nc0 = blockIdx.y * 64;
    const int lrow = tid >> 2;            // 0..63
    const int lk4  = (tid & 3) << 2;      // 0,4,8,12

    const int gr = m0 + lrow;
    const float* srow = nullptr;
    if (gr < n0)            srow = S0 + (size_t)gr * K;
    else if (gr < n0 + n1)  srow = S1 + (size_t)(gr - n0) * K;
    else if (gr < Mtot)     srow = S2;               // single virtual row
    const float* wrow = W + (size_t)(nc0 + lrow) * K;

    float acc[4][4] = {};
    for (int k0 = 0; k0 < K; k0 += 16) {
        float4 va = make_float4(0.f, 0.f, 0.f, 0.f);
        if (srow) va = *(const float4*)(srow + k0 + lk4);
        const float4 vb = *(const float4*)(wrow + k0 + lk4);
        As[lk4+0][lrow] = va.x; As[lk4+1][lrow] = va.y;
        As[lk4+2][lrow] = va.z; As[lk4+3][lrow] = va.w;
        Bs[lk4+0][lrow] = vb.x; Bs[lk4+1][lrow] = vb.y;
        Bs[lk4+2][lrow] = vb.z; Bs[lk4+3][lrow] = vb.w;
        __syncthreads();
        #pragma unroll
        for (int kk = 0; kk < 16; ++kk) {
            const float4 a4 = *(const float4*)&As[kk][ty << 2];
            const float4 b4 = *(const float4*)&Bs[kk][tx << 2];
            const float av[4] = {a4.x, a4.y, a4.z, a4.w};
            const float bv[4] = {b4.x, b4.y, b4.z, b4.w};
            #pragma unroll
            for (int i2 = 0; i2 < 4; ++i2)
                #pragma unroll
                for (int j2 = 0; j2 < 4; ++j2)
                    acc[i2][j2] = fmaf(av[i2], bv[j2], acc[i2][j2]);
        }
        __syncthreads();
    }
    #pragma unroll
    for (int i2 = 0; i2 < 4; ++i2) {
        const int grr = m0 + (ty << 2) + i2;
        if (grr >= Mtot) continue;
        #pragma unroll
        for (int j2 = 0; j2 < 4; ++j2) {
            const int gc = nc0 + (tx << 2) + j2;
            const float vv = acc[i2][j2] + bias[gc];
            C[(size_t)grr * EDIM + gc] = fmaxf(vv, 0.0f);
        }
    }
}

// ---------------------------------------------------------------------------
// Per-pair scaled edit-cost matrix (33x33), written dense (zeros outside valid)
// Emb layout: rows [0,Ns) = source, [Ns, Ns+Nt) = target, row Ns+Nt = virtual.
// ---------------------------------------------------------------------------
__global__ __launch_bounds__(256)
void k_costs(const float* __restrict__ Emb, const int* __restrict__ len_s,
             const int* __restrict__ len_t, int Ns, int Nt,
             float* __restrict__ costs) {
    __shared__ alignas(16) float Asl[LMAXP1 * EDIM];      // ~33.8 KB
    __shared__ float dtile[LMAXP1 * LMAXP1];
    __shared__ float na[LMAXP1], nb[LMAXP1];
    __shared__ float red[256];
    __shared__ float s_scale;
    const int p = blockIdx.x, tid = threadIdx.x;
    const int n = len_s[p], m = len_t[p];
    int offs = 0, offt = 0;
    for (int j = 0; j < p; ++j) { offs += len_s[j]; offt += len_t[j]; }  // uniform
    const int veRow = Ns + Nt;
    const int tbase = Ns + offt;                 // target rows base

    for (int idx = tid; idx < (n + 1) * (EDIM / 4); idx += 256) {
        const int r = idx >> 6, c = idx & 63;
        const float* src = (r < n) ? (Emb + (size_t)(offs + r) * EDIM)
                                   : (Emb + (size_t)veRow * EDIM);
        ((float4*)Asl)[r * 64 + c] = ((const float4*)src)[c];
    }
    __syncthreads();

    if (tid <= n) {                                  // ||a_i||^2
        const float4* a4 = (const float4*)(Asl + tid * EDIM);
        float s = 0.f;
        for (int k = 0; k < 64; ++k) {
            const float4 a = a4[k];
            s = fmaf(a.x, a.x, s); s = fmaf(a.y, a.y, s);
            s = fmaf(a.z, a.z, s); s = fmaf(a.w, a.w, s);
        }
        na[tid] = s;
    } else if (tid >= 64 && tid - 64 <= m) {          // ||b_j||^2
        const int j = tid - 64;
        const float* src = (j < m) ? (Emb + (size_t)(tbase + j) * EDIM)
                                   : (Emb + (size_t)veRow * EDIM);
        const float4* b4 = (const float4*)src;
        float s = 0.f;
        for (int k = 0; k < 64; ++k) {
            const float4 b = b4[k];
            s = fmaf(b.x, b.x, s); s = fmaf(b.y, b.y, s);
            s = fmaf(b.z, b.z, s); s = fmaf(b.w, b.w, s);
        }
        nb[j] = s;
    }
    __syncthreads();

    float lsum = 0.f;
    const int m1 = m + 1;
    const int cells = (n + 1) * m1;
    for (int c = tid; c < cells; c += 256) {
        const int i = c / m1, j = c - i * m1;
        const float* brow = (j < m) ? (Emb + (size_t)(tbase + j) * EDIM)
                                    : (Emb + (size_t)veRow * EDIM);
        const float4* a4 = (const float4*)(Asl + i * EDIM);
        const float4* b4 = (const float4*)brow;
        float dot = 0.f;
        #pragma unroll 8
        for (int k = 0; k < 64; ++k) {
            const float4 a = a4[k], b = b4[k];
            dot = fmaf(a.x, b.x, dot); dot = fmaf(a.y, b.y, dot);
            dot = fmaf(a.z, b.z, dot); dot = fmaf(a.w, b.w, dot);
        }
        const float sq = fmaxf(na[i] + nb[j] - 2.0f * dot, 0.0f);
        const float d  = (sq > 0.0f) ? sqrtf(sq) : 0.0f;
        dtile[i * LMAXP1 + j] = d;
        lsum += d;
    }
    red[tid] = lsum;
    __syncthreads();
    for (int s = 128; s > 0; s >>= 1) {
        if (tid < s) red[tid] += red[tid + s];
        __syncthreads();
    }
    if (tid == 0) s_scale = (float)(n * m) / red[0];
    __syncthreads();
    const float scale = s_scale;
    for (int idx = tid; idx < LMAXP1 * LMAXP1; idx += 256) {
        const int i = idx / LMAXP1, j = idx - i * LMAXP1;
        const float v = (i <= n && j <= m) ? dtile[i * LMAXP1 + j] * scale : 0.0f;
        costs[(size_t)p * (LMAXP1 * LMAXP1) + idx] = v;
    }
}

// ---------------------------------------------------------------------------
// LAP (Jonker-Volgenant + column-reduction/greedy init), exact.
// Valid because: init gives a feasible dual (u=0, v=colmin) + consistent
// partial matching; JV's Dijkstra from each remaining free row preserves
// optimality, and the optimal assignment (restricted to the cells the output
// can see) is unique for these continuous random costs. Leftover insertion
// rows terminate in 1 Dijkstra step (0-cost edge to a free dummy column).
// ---------------------------------------------------------------------------
__device__ inline int rdlane_i(int v, int l) { return __builtin_amdgcn_readlane(v, l); }
__device__ inline float rdlane_f(float v, int l) {
    return __int_as_float(__builtin_amdgcn_readlane(__float_as_int(v), l));
}
// full-wave min; result broadcast via readlane 63.
__device__ inline float wave_min64(float x) {
#define DPPMIN(ctrl) { int t_ = __builtin_amdgcn_update_dpp(               \
        __float_as_int(x), __float_as_int(x), (ctrl), 0xf, 0xf, false);    \
        x = fminf(x, __int_as_float(t_)); }
    DPPMIN(0xB1)   // quad_perm xor1
    DPPMIN(0x4E)   // quad_perm xor2
    DPPMIN(0x141)  // row_half_mirror xor4
    DPPMIN(0x140)  // row_mirror xor8
    DPPMIN(0x142)  // row_bcast15
    DPPMIN(0x143)  // row_bcast31
#undef DPPMIN
    return rdlane_f(x, 63);
}

__global__ __launch_bounds__(64)
void k_lap(const float* __restrict__ costs, const int* __restrict__ len_s,
           const int* __restrict__ len_t, float* __restrict__ aligns,
           float* __restrict__ geds) {
    __shared__ float ec[LMAXP1 * LMAXP1];
    __shared__ float Cs[62 * 64];           // rows 1..N at [r*64 + col]
    const int p = blockIdx.x, lane = threadIdx.x;
    const int n = len_s[p], m = len_t[p], N = n + m;
    const float* cp = costs + (size_t)p * (LMAXP1 * LMAXP1);
    for (int idx = lane; idx < LMAXP1 * LMAXP1; idx += 64) ec[idx] = cp[idx];
    __syncthreads();

    // Build expanded (N x N) LSAPE matrix exactly like _lsape_align (fp32).
    const bool vec = (lane >= 1 && lane <= N);
    for (int r = 1; r <= N; ++r) {
        float cv = CINF;
        const int i0b = r - 1, j0b = lane - 1;
        if (vec) {
            if (i0b < n) cv = (j0b < m) ? ec[i0b * LMAXP1 + j0b]
                                        : ((j0b == m + i0b) ? ec[i0b * LMAXP1 + m] : CINF);
            else         cv = (j0b < m) ? ((i0b - n == j0b) ? ec[n * LMAXP1 + j0b] : CINF)
                                        : 0.0f;
        }
        Cs[(r << 6) + lane] = cv;
    }
    __syncthreads();

    // ---- Column reduction: v_j = min_i C_ij, track first argmin row ----
    float v_l = 0.0f;
    int amin_l = 0;
    if (vec) {
        float best = FBIG;
        for (int r = 1; r <= N; ++r) {
            const float c = Cs[(r << 6) + lane];
            if (c < best) { best = c; amin_l = r; }
        }
        v_l = best;
    }
    // ---- Greedy assignment: column j -> argmin row if that row is free ----
    int p_l = 0;                                  // p[col]=row (0 = free); lane=col
    unsigned long long rowfree = ((N < 64) ? ((1ull << N) - 1ull) << 1
                                           : ~1ull);   // bits 1..N set
    for (int j = 1; j <= N; ++j) {
        const int ai = rdlane_i(amin_l, j);
        if ((rowfree >> ai) & 1ull) {
            if (lane == j) p_l = ai;
            rowfree &= ~(1ull << ai);
        }
    }

    // ---- JV Dijkstra for each remaining free row (body identical to R4) ----
    float ucol = 0.0f, minv_l = FBIG;             // ucol = u[p[lane]] (all 0 now)
    int way_l = 0;

    for (int i = 1; i <= N; ++i) {
        if (!((rowfree >> i) & 1ull)) continue;   // uniform branch
        if (lane == 0) { p_l = i; ucol = 0.0f; }  // p[0]=i, u[i]=0
        minv_l = FBIG;
        int used_l = 0;
        int j0 = 0;
        while (true) {
            if (lane == j0) used_l = 1;             // used[j0] = True
            const int   i0   = rdlane_i(p_l, j0);   // i0 = p[j0]
            const float u_i0 = rdlane_f(ucol, j0);  // u[p[j0]]
            const float cur  = Cs[(i0 << 6) + lane] - u_i0 - v_l;
            const bool unused = vec && !used_l;
            if (unused && cur < minv_l) { minv_l = cur; way_l = j0; }
            const float masked = unused ? minv_l : FBIG;
            const float mv = wave_min64(masked);
            const unsigned long long ball = __ballot(masked == mv);
            int j1 = __ffsll(ball) - 1;             // first-index argmin
            j1 = __builtin_amdgcn_readfirstlane(j1);
            const float delta = mv;
            if (used_l) { ucol += delta; v_l -= delta; }
            if (unused) minv_l -= delta;
            j0 = j1;
            const int pj = rdlane_i(p_l, j0);
            if (pj == 0) break;
        }
        // augment: while j0: j1=way[j0]; p[j0]=p[j1]; j0=j1  (u follows p)
        int jj = j0;
        while (jj != 0) {
            const int   j1a = rdlane_i(way_l, jj);
            const int   pn  = rdlane_i(p_l, j1a);
            const float un  = rdlane_f(ucol, j1a);
            if (lane == jj) { p_l = pn; ucol = un; }
            jj = j1a;
        }
    }

    // ---- outputs: aligns (0/1 as float), geds ----
    float* ap = aligns + (size_t)p * (LMAXP1 * LMAXP1);
    for (int idx = lane; idx < LMAXP1 * LMAXP1; idx += 64) ap[idx] = 0.0f;
    __syncthreads();
    float gedv = 0.0f;
    if (vec) {
        const int r0 = p_l - 1;                  // row assigned to column (lane)
        const int c0 = lane - 1;
        const int rr = (r0 < n) ? r0 : n;
        const int cc = (c0 < m) ? c0 : m;
        if (!(r0 >= n && c0 >= m)) {             // dummy-dummy -> align[n][m], stays 0
            ap[rr * LMAXP1 + cc] = 1.0f;
            gedv = ec[rr * LMAXP1 + cc];
        }
    }
    #pragma unroll
    for (int off = 32; off > 0; off >>= 1) gedv += __shfl_xor(gedv, off);
    if (lane == 0) geds[p] = gedv / (float)(n + m);
}

// ---------------------------------------------------------------------------
extern "C" void kernel_launch(void* const* d_in, const int* in_sizes, int n_in,
                              void* d_out, int out_size, void* d_ws, size_t ws_size,
                              hipStream_t stream) {
    const float* x_s = (const float*)d_in[0];
    const float* x_t = (const float*)d_in[1];
    const float* W1  = (const float*)d_in[2];
    const float* b1  = (const float*)d_in[3];
    const float* W2  = (const float*)d_in[4];
    const float* b2  = (const float*)d_in[5];
    const float* ve  = (const float*)d_in[6];
    const int* len_s = (const int*)d_in[7];
    const int* len_t = (const int*)d_in[8];
    const int P    = in_sizes[7];
    const int Ns   = in_sizes[0] / 2048;
    const int Nt   = in_sizes[1] / 2048;
    const int Mtot = Ns + Nt + 1;

    float* H   = (float*)d_ws;
    float* Emb = H + (size_t)Mtot * EDIM;

    float* out_aligns = (float*)d_out;
    float* out_costs  = out_aligns + (size_t)P * LMAXP1 * LMAXP1;
    float* out_geds   = out_costs  + (size_t)P * LMAXP1 * LMAXP1;

    const dim3 b256(256);
    const dim3 g1((Mtot + 63) / 64, EDIM / 64);
    k_embed_gemm<<<g1, b256, 0, stream>>>(x_s, Ns, x_t, Nt, ve, W1, b1, H, Mtot, 2048);
    k_embed_gemm<<<g1, b256, 0, stream>>>(H, Mtot, nullptr, 0, nullptr, W2, b2, Emb, Mtot, 256);
    k_costs<<<dim3(P), b256, 0, stream>>>(Emb, len_s, len_t, Ns, Nt, out_costs);
    k_lap<<<dim3(P), dim3(64), 0, stream>>>(out_costs, len_s, len_t, out_aligns, out_geds);
}